// Round 4
// baseline (254.066 us; speedup 1.0000x reference)
//
#include <hip/hip_runtime.h>
#include <math.h>

#define HFD 128
#define WFD 128
#define DFD 512
#define KA  4
#define NA  (HFD*WFD*KA)      // 65536
#define MAXD 512
#define HID 1024
#define FIN 4608              // 3*3*512
#define CMAX 2048
#define TAUF 0.5f
#define NMS_THR 0.3f
#define SPLITK 8

typedef __bf16 bf16x8 __attribute__((ext_vector_type(8)));
typedef float  floatx4 __attribute__((ext_vector_type(4)));

__device__ __forceinline__ unsigned short f2bf(float x) {
    unsigned u = __float_as_uint(x);
    unsigned r = (u + 0x7FFFu + ((u >> 16) & 1u)) >> 16;   // RNE
    return (unsigned short)r;
}

// ------------------------------------------------------ scores only
__global__ void score_kernel(const float* __restrict__ rpn_obj,
                             float* __restrict__ scores) {
    int n = blockIdx.x * blockDim.x + threadIdx.x;
    if (n >= NA) return;
    float2 o = ((const float2*)rpn_obj)[n];   // == rpn_obj[cell*8+2k ..]
    float o0 = o.x, o1 = o.y;
    float m  = fmaxf(o0, o1);
    float e0 = expf(o0 - m), e1 = expf(o1 - m);
    scores[n] = e1 / (e0 + e1);               // same formula as before
}

// ---- fused: hist + threshold + compact + sort + decode + IoU + NMS
__global__ __launch_bounds__(1024)
void select_kernel(const float* __restrict__ scores,
                   const float* __restrict__ rpn_reg,
                   const float* __restrict__ anchors,
                   float* __restrict__ sel,          // 512 x float4
                   float* __restrict__ top_score,    // 512
                   unsigned* __restrict__ valid_g,   // 512
                   unsigned* __restrict__ keep_g) {  // 512
    __shared__ unsigned long long keys[CMAX];        // 16 KB (hist/scan alias)
    __shared__ float4 selS[MAXD];                    // 8 KB
    __shared__ unsigned long long maskS[MAXD * 8];   // 32 KB
    __shared__ unsigned cntS;

    unsigned* hist = (unsigned*)keys;                // 1025 u32 = 4100 B
    unsigned* Ssc  = (unsigned*)(keys + 520);        // 1024 u32, no overlap

    int tid = threadIdx.x;
    int wave = tid >> 6, lane = tid & 63;

    // ---- phase 1: histogram of score bit-buckets
    for (int i = tid; i < 1025; i += 1024) hist[i] = 0u;
    if (tid == 0) cntS = 0u;
    __syncthreads();
    for (int n = tid; n < NA; n += 1024) {
        float s = scores[n];
        if (s > TAUF) {
            unsigned b = (__float_as_uint(s) - 0x3F000000u) >> 13;  // 0..1024
            atomicAdd(&hist[b], 1u);
        }
    }
    __syncthreads();

    // ---- phase 2: suffix-sum over buckets 1..1024, find threshold bucket
    unsigned sv = hist[tid + 1];                     // thread t <-> bucket t+1
    __syncthreads();                                 // hist reads done
    Ssc[tid] = sv;
    __syncthreads();
    for (int d = 1; d < 1024; d <<= 1) {
        unsigned add = (tid + d < 1024) ? Ssc[tid + d] : 0u;
        __syncthreads();
        Ssc[tid] += add;
        __syncthreads();
    }
    __shared__ unsigned thrS;
    if (tid == 0 && Ssc[0] < MAXD) thrS = 0u;
    {
        unsigned Scur = Ssc[tid];
        unsigned Snxt = (tid == 1023) ? 0u : Ssc[tid + 1];
        if (Scur >= MAXD && Snxt < MAXD) thrS = (unsigned)(tid + 1);
    }
    __syncthreads();
    unsigned thr = thrS;
    __syncthreads();                                 // Ssc/hist dead now

    // ---- phase 3: compact candidates into keys
    for (int n = tid; n < NA; n += 1024) {
        float s = scores[n];
        if (s > TAUF) {
            unsigned bits = __float_as_uint(s);
            unsigned b = (bits - 0x3F000000u) >> 13;
            if (b >= thr) {
                unsigned pos = atomicAdd(&cntS, 1u);
                if (pos < CMAX)
                    keys[pos] = ((unsigned long long)bits << 32) |
                                (unsigned long long)(~(unsigned)n);
            }
        }
    }
    __syncthreads();
    unsigned cnt = cntS; if (cnt > CMAX) cnt = CMAX;
    int SN = (cnt <= 1024) ? 1024 : CMAX;
    for (int i = tid; i < SN; i += 1024)
        if (i >= (int)cnt) keys[i] = 0ULL;
    __syncthreads();

    // ---- phase 4: bitonic sort descending over SN
    for (int k = 2; k <= SN; k <<= 1) {
        for (int j = k >> 1; j > 0; j >>= 1) {
            for (int i = tid; i < SN; i += 1024) {
                int ixj = i ^ j;
                if (ixj > i) {
                    unsigned long long a = keys[i], b = keys[ixj];
                    bool up = ((i & k) == 0);
                    if ((a < b) == up) { keys[i] = b; keys[ixj] = a; }
                }
            }
            __syncthreads();
        }
    }

    // ---- phase 5: decode top-512 boxes (same fp32 formulas as before)
    if (tid < MAXD) {
        unsigned long long e = keys[tid];
        unsigned sbits = (unsigned)(e >> 32);
        bool v = (sbits != 0u);
        unsigned idx = v ? (unsigned)(~(unsigned)e) : 0u;
        int cell = idx >> 2, kk = idx & 3;
        float4 rg = *(const float4*)&rpn_reg[cell * 16 + 4 * kk];
        float4 an = *(const float4*)&anchors[idx * 4];
        float acx = an.x + an.z * 0.5f;
        float acy = an.y + an.w * 0.5f;
        float cx = acx + rg.x * an.z;
        float cy = acy + rg.y * an.w;
        float w  = an.z * expf(rg.z);
        float h  = an.w * expf(rg.w);
        float4 box = make_float4(cx - 0.5f * w, cy - 0.5f * h, w, h);
        selS[tid] = box;
        ((float4*)sel)[tid] = box;
        top_score[tid] = v ? __uint_as_float(sbits) : 0.0f;
        valid_g[tid]   = v ? 1u : 0u;
    }
    __syncthreads();

    // ---- phase 6: IoU bit-matrix (only words t <= row's group needed)
    for (int it = 0; it < 32; ++it) {
        int i = wave + 16 * it;                  // balanced across waves
        float4 bi = selS[i];
        float x2i = bi.x + bi.z, y2i = bi.y + bi.w;
        float ai = bi.z * bi.w;
        int g = i >> 6;
        for (int t = 0; t <= g; ++t) {
            float4 bj = selS[t * 64 + lane];
            float x2j = bj.x + bj.z, y2j = bj.y + bj.w;
            float aj = bj.z * bj.w;
            float ix = fmaxf(0.0f, fminf(x2i, x2j) - fmaxf(bi.x, bj.x));
            float iy = fmaxf(0.0f, fminf(y2i, y2j) - fmaxf(bi.y, bj.y));
            float inter = ix * iy;
            float iou = inter / (ai + aj - inter + 1e-8f);
            unsigned long long bal = __ballot(iou > NMS_THR);
            if (lane == 0) maskS[i * 8 + t] = bal;
        }
    }
    __syncthreads();

    // ---- phase 7: ballot-pipelined sequential NMS on wave 0
    if (wave == 0) {
        unsigned long long keepw[8];
#pragma unroll
        for (int g = 0; g < 8; ++g) {
            unsigned long long w_cur[8];
#pragma unroll
            for (int t = 0; t < 8; ++t)
                w_cur[t] = (t <= g) ? maskS[(g * 64 + lane) * 8 + t] : 0ULL;
            unsigned long long vb =
                __ballot(((unsigned)(keys[g * 64 + lane] >> 32)) != 0u);
            bool pre = false;
#pragma unroll
            for (int t = 0; t < 8; ++t)
                if (t < g) pre = pre || ((w_cur[t] & keepw[t]) != 0ULL);
            unsigned long long alive = vb & ~__ballot(pre);
            unsigned long long intra = w_cur[g];
            unsigned long long kg = 0ULL;
#pragma unroll
            for (int b = 0; b < 64; ++b) {
                unsigned long long sup = __ballot((intra >> b) & 1ULL);
                if ((alive >> b) & 1ULL) {      // wave-uniform branch
                    kg |= 1ULL << b;
                    alive &= ~sup;
                }
            }
            keepw[g] = kg;
            keep_g[g * 64 + lane] = (unsigned)((kg >> lane) & 1ULL);
        }
    }
}

// ------------------------------------------- ROI align (bf16 output)
__global__ __launch_bounds__(256)
void roialign_kernel(const float* __restrict__ feat,
                     const float* __restrict__ sel,
                     unsigned short* __restrict__ pooled) {
    int mrow = blockIdx.x;
    int c = threadIdx.x;           // channels c and c+256
    float4 b = ((const float4*)sel)[mrow];
    float bx = b.x, by = b.y, bw = b.z, bh = b.w;
    float vmax0[9], vmax1[9];
#pragma unroll
    for (int t = 0; t < 9; ++t) { vmax0[t] = -INFINITY; vmax1[t] = -INFINITY; }
#pragma unroll
    for (int p = 0; p < 6; ++p) {
        float fy = (by + ((float)p + 0.5f) / 6.0f * bh) / 16.0f - 0.5f;
        fy = fminf(fmaxf(fy, 0.0f), 127.0f);
        int y0 = (int)floorf(fy);
        int y1 = min(y0 + 1, 127);
        float wy = fy - (float)y0;
#pragma unroll
        for (int q = 0; q < 6; ++q) {
            float fx = (bx + ((float)q + 0.5f) / 6.0f * bw) / 16.0f - 0.5f;
            fx = fminf(fmaxf(fx, 0.0f), 127.0f);
            int x0 = (int)floorf(fx);
            int x1 = min(x0 + 1, 127);
            float wx = fx - (float)x0;
            const float* f00 = feat + (y0 * WFD + x0) * DFD;
            const float* f01 = feat + (y0 * WFD + x1) * DFD;
            const float* f10 = feat + (y1 * WFD + x0) * DFD;
            const float* f11 = feat + (y1 * WFD + x1) * DFD;
            float w00 = (1.0f - wy) * (1.0f - wx);
            float w01 = (1.0f - wy) * wx;
            float w10 = wy * (1.0f - wx);
            float w11 = wy * wx;
            int t = (p >> 1) * 3 + (q >> 1);
            float v0 = f00[c] * w00 + f01[c] * w01 + f10[c] * w10 + f11[c] * w11;
            float v1 = f00[c + 256] * w00 + f01[c + 256] * w01 +
                       f10[c + 256] * w10 + f11[c + 256] * w11;
            vmax0[t] = fmaxf(vmax0[t], v0);
            vmax1[t] = fmaxf(vmax1[t], v1);
        }
    }
#pragma unroll
    for (int t = 0; t < 9; ++t) {
        pooled[mrow * FIN + t * DFD + c] = f2bf(vmax0[t]);
        pooled[mrow * FIN + t * DFD + c + 256] = f2bf(vmax1[t]);
    }
}

// -------------- both weight transposes (fp32 [K][N] -> bf16 [N][K])
__global__ __launch_bounds__(256)
void transpose_both_kernel(const float* __restrict__ W1,
                           unsigned short* __restrict__ W1t,
                           const float* __restrict__ W2,
                           unsigned short* __restrict__ W2t) {
    __shared__ float tile[32][33];
    int b = blockIdx.x;
    const float* W; unsigned short* Wt; int K, N;
    if (b < (FIN / 32) * (HID / 32)) { W = W1; Wt = W1t; K = FIN; N = HID; }
    else { b -= (FIN / 32) * (HID / 32); W = W2; Wt = W2t; K = HID; N = HID; }
    int bn = (b & (N / 32 - 1)) * 32;
    int bk = (b / (N / 32)) * 32;
    int tx = threadIdx.x & 31, ty = threadIdx.x >> 5;   // ty 0..7
#pragma unroll
    for (int r = 0; r < 32; r += 8)
        tile[ty + r][tx] = W[(long)(bk + ty + r) * N + bn + tx];
    __syncthreads();
#pragma unroll
    for (int r = 0; r < 32; r += 8)
        Wt[(long)(bn + ty + r) * K + bk + tx] = f2bf(tile[tx][ty + r]);
}

// --------------------------------------- bf16 MFMA GEMM with split-K
#define LDSTRIDE 40
__global__ __launch_bounds__(256)
void mfma_gemm_kernel(const unsigned short* __restrict__ A,
                      const unsigned short* __restrict__ Bt,
                      float* __restrict__ Cpart,
                      int M, int N, int K) {
    __shared__ unsigned short As[64 * LDSTRIDE];
    __shared__ unsigned short Bs[64 * LDSTRIDE];
    int tid = threadIdx.x;
    int wave = tid >> 6, lane = tid & 63;
    int bm = blockIdx.y * 64, bn = blockIdx.x * 64;
    int KC = K / SPLITK;
    int ks = blockIdx.z * KC;

    floatx4 acc[4] = {};
    int lr = tid >> 2;            // 0..63  staging row
    int lk = (tid & 3) << 3;      // 0,8,16,24  staging k-offset
    int frow = lane & 15, quad = lane >> 4;

    const unsigned short* Ap = A + (long)(bm + lr) * K + lk;
    const unsigned short* Bp = Bt + (long)(bn + lr) * K + lk;

    for (int k0 = ks; k0 < ks + KC; k0 += 32) {
        uint4 av = *(const uint4*)(Ap + k0);
        uint4 bv = *(const uint4*)(Bp + k0);
        *(uint4*)&As[lr * LDSTRIDE + lk] = av;
        *(uint4*)&Bs[lr * LDSTRIDE + lk] = bv;
        __syncthreads();
        bf16x8 af = *(const bf16x8*)&As[(wave * 16 + frow) * LDSTRIDE + quad * 8];
#pragma unroll
        for (int t = 0; t < 4; ++t) {
            bf16x8 bfv = *(const bf16x8*)&Bs[(t * 16 + frow) * LDSTRIDE + quad * 8];
            acc[t] = __builtin_amdgcn_mfma_f32_16x16x32_bf16(af, bfv, acc[t], 0, 0, 0);
        }
        __syncthreads();
    }

    float* Cp = Cpart + (long)blockIdx.z * M * N;
#pragma unroll
    for (int t = 0; t < 4; ++t) {
#pragma unroll
        for (int r = 0; r < 4; ++r) {
            int m = bm + wave * 16 + quad * 4 + r;
            int n = bn + t * 16 + frow;
            Cp[(long)m * N + n] = acc[t][r];
        }
    }
}

// --------------------- split-K reduce + bias + relu -> bf16
__global__ __launch_bounds__(256)
void reduce_bias_relu_kernel(const float* __restrict__ Cpart,
                             const float* __restrict__ bias,
                             unsigned short* __restrict__ out_bf,
                             int MN, int N) {
    int i4 = (blockIdx.x * blockDim.x + threadIdx.x) * 4;
    if (i4 >= MN) return;
    float4 s = *(const float4*)&Cpart[i4];
#pragma unroll
    for (int z = 1; z < SPLITK; ++z) {
        float4 p = *(const float4*)&Cpart[(long)z * MN + i4];
        s.x += p.x; s.y += p.y; s.z += p.z; s.w += p.w;
    }
    int n = i4 & (N - 1);
    float4 bi = *(const float4*)&bias[n];
    s.x = fmaxf(s.x + bi.x, 0.0f);
    s.y = fmaxf(s.y + bi.y, 0.0f);
    s.z = fmaxf(s.z + bi.z, 0.0f);
    s.w = fmaxf(s.w + bi.w, 0.0f);
    uint2 o;
    o.x = (unsigned)f2bf(s.x) | ((unsigned)f2bf(s.y) << 16);
    o.y = (unsigned)f2bf(s.z) | ((unsigned)f2bf(s.w) << 16);
    *(uint2*)&out_bf[i4] = o;
}

// --- fused: split-K reduce (GEMM2) + bias2 + relu + W3 dot + epilogue
__global__ __launch_bounds__(256)
void rowhead_kernel(const float* __restrict__ Cpart,
                    const float* __restrict__ b2,
                    const float* __restrict__ W3,
                    const float* __restrict__ b3,
                    const float* __restrict__ sel,
                    const float* __restrict__ top_score,
                    const unsigned* __restrict__ valid,
                    const unsigned* __restrict__ keep,
                    float* __restrict__ out) {
    __shared__ float red[4][4];
    int r = blockIdx.x, t = threadIdx.x;
    int wave = t >> 6, lane = t & 63;
    int c = t * 4;
    const int MN = MAXD * HID;
    float4 s = *(const float4*)&Cpart[(long)r * HID + c];
#pragma unroll
    for (int z = 1; z < SPLITK; ++z) {
        float4 p = *(const float4*)&Cpart[(long)z * MN + (long)r * HID + c];
        s.x += p.x; s.y += p.y; s.z += p.z; s.w += p.w;
    }
    float4 bi = *(const float4*)&b2[c];
    float h[4];
    h[0] = fmaxf(s.x + bi.x, 0.0f);
    h[1] = fmaxf(s.y + bi.y, 0.0f);
    h[2] = fmaxf(s.z + bi.z, 0.0f);
    h[3] = fmaxf(s.w + bi.w, 0.0f);
    float a0 = 0.f, a1 = 0.f, a2 = 0.f, a3 = 0.f;
#pragma unroll
    for (int i = 0; i < 4; ++i) {
        float4 w = *(const float4*)&W3[(c + i) * 4];
        a0 += h[i] * w.x; a1 += h[i] * w.y;
        a2 += h[i] * w.z; a3 += h[i] * w.w;
    }
#pragma unroll
    for (int off = 32; off > 0; off >>= 1) {
        a0 += __shfl_down(a0, off);
        a1 += __shfl_down(a1, off);
        a2 += __shfl_down(a2, off);
        a3 += __shfl_down(a3, off);
    }
    if (lane == 0) {
        red[wave][0] = a0; red[wave][1] = a1;
        red[wave][2] = a2; red[wave][3] = a3;
    }
    __syncthreads();
    if (t == 0) {
        float d0 = red[0][0] + red[1][0] + red[2][0] + red[3][0] + b3[0];
        float d1 = red[0][1] + red[1][1] + red[2][1] + red[3][1] + b3[1];
        float d2 = red[0][2] + red[1][2] + red[2][2] + red[3][2] + b3[2];
        float d3 = red[0][3] + red[1][3] + red[2][3] + red[3][3] + b3[3];
        if (keep[r] != 0u) {
            float4 b = ((const float4*)sel)[r];
            float acx = b.x + 0.5f * b.z;
            float acy = b.y + 0.5f * b.w;
            float cx = acx + d0 * b.z;
            float cy = acy + d1 * b.w;
            float nw = b.z * expf(d2);
            float nh = b.w * expf(d3);
            out[r * 5 + 0] = cx - 0.5f * nw;
            out[r * 5 + 1] = cy - 0.5f * nh;
            out[r * 5 + 2] = nw;
            out[r * 5 + 3] = nh;
            out[r * 5 + 4] = (valid[r] != 0u) ? top_score[r] : 0.0f;
        } else {
            out[r * 5 + 0] = 0.0f;
            out[r * 5 + 1] = 0.0f;
            out[r * 5 + 2] = 0.0f;
            out[r * 5 + 3] = 0.0f;
            out[r * 5 + 4] = 0.0f;
        }
    }
}

// ---------------------------------------------------------------- host
extern "C" void kernel_launch(void* const* d_in, const int* in_sizes, int n_in,
                              void* d_out, int out_size, void* d_ws, size_t ws_size,
                              hipStream_t stream) {
    const float* features = (const float*)d_in[0];
    const float* rpn_obj  = (const float*)d_in[1];
    const float* rpn_reg  = (const float*)d_in[2];
    const float* anchors  = (const float*)d_in[3];
    const float* W1 = (const float*)d_in[4];
    const float* b1 = (const float*)d_in[5];
    const float* W2 = (const float*)d_in[6];
    const float* b2 = (const float*)d_in[7];
    const float* W3 = (const float*)d_in[8];
    const float* b3 = (const float*)d_in[9];
    float* out = (float*)d_out;

    char* ws = (char*)d_ws;
    size_t off = 0;
    auto alloc = [&](size_t bytes) {
        char* p = ws + off;
        off += (bytes + 255) & ~(size_t)255;
        return p;
    };
    float*    scores    = (float*)alloc(NA * sizeof(float));
    float*    sel       = (float*)alloc(MAXD * 4 * sizeof(float));
    float*    top_score = (float*)alloc(MAXD * sizeof(float));
    unsigned* valid     = (unsigned*)alloc(MAXD * sizeof(unsigned));
    unsigned* keep      = (unsigned*)alloc(MAXD * sizeof(unsigned));
    unsigned short* pooled = (unsigned short*)alloc((size_t)MAXD * FIN * 2);
    unsigned short* W1t = (unsigned short*)alloc((size_t)FIN * HID * 2);
    unsigned short* W2t = (unsigned short*)alloc((size_t)HID * HID * 2);
    unsigned short* h1  = (unsigned short*)alloc((size_t)MAXD * HID * 2);
    float*    Cpart     = (float*)alloc((size_t)SPLITK * MAXD * HID * sizeof(float));
    (void)ws_size; (void)in_sizes; (void)n_in; (void)out_size;

    score_kernel<<<NA / 256, 256, 0, stream>>>(rpn_obj, scores);
    select_kernel<<<1, 1024, 0, stream>>>(scores, rpn_reg, anchors,
                                          sel, top_score, valid, keep);
    transpose_both_kernel<<<(FIN / 32) * (HID / 32) + (HID / 32) * (HID / 32),
                            256, 0, stream>>>(W1, W1t, W2, W2t);
    roialign_kernel<<<MAXD, 256, 0, stream>>>(features, sel, pooled);

    const int MN = MAXD * HID;
    mfma_gemm_kernel<<<dim3(HID / 64, MAXD / 64, SPLITK), 256, 0, stream>>>(
        pooled, W1t, Cpart, MAXD, HID, FIN);
    reduce_bias_relu_kernel<<<MN / 4 / 256, 256, 0, stream>>>(
        Cpart, b1, h1, MN, HID);
    mfma_gemm_kernel<<<dim3(HID / 64, MAXD / 64, SPLITK), 256, 0, stream>>>(
        h1, W2t, Cpart, MAXD, HID, HID);
    rowhead_kernel<<<MAXD, 256, 0, stream>>>(Cpart, b2, W3, b3, sel,
                                             top_score, valid, keep, out);
}

// Round 5
// 244.189 us; speedup vs baseline: 1.0404x; 1.0404x over previous
//
#include <hip/hip_runtime.h>
#include <math.h>

#define HFD 128
#define WFD 128
#define DFD 512
#define KA  4
#define NA  (HFD*WFD*KA)      // 65536
#define MAXD 512
#define HID 1024
#define FIN 4608              // 3*3*512
#define CMAX 2048
#define NBUCK 1025
#define BINCAP 64
#define TAUF 0.5f
#define NMS_THR 0.3f
#define SPLITK 8

typedef __bf16 bf16x8 __attribute__((ext_vector_type(8)));
typedef float  floatx4 __attribute__((ext_vector_type(4)));

__device__ __forceinline__ unsigned short f2bf(float x) {
    unsigned u = __float_as_uint(x);
    unsigned r = (u + 0x7FFFu + ((u >> 16) & 1u)) >> 16;   // RNE
    return (unsigned short)r;
}

// ------------------------------------------------- zero the histogram
__global__ void init_kernel(unsigned* __restrict__ hist) {
    int t = threadIdx.x;
    for (int i = t; i < NBUCK; i += 1024) hist[i] = 0u;
}

// ---- grid-wide front: score+bucket-bin (blocks 0..255) + transposes
__global__ __launch_bounds__(256)
void front_kernel(const float* __restrict__ rpn_obj,
                  unsigned* __restrict__ hist,
                  unsigned long long* __restrict__ bins,
                  const float* __restrict__ W1,
                  unsigned short* __restrict__ W1t,
                  const float* __restrict__ W2,
                  unsigned short* __restrict__ W2t) {
    __shared__ float tile[32][33];
    int b = blockIdx.x;
    if (b < 256) {
        // scores: softmax(o)[1], bucket by float bits, bin the key
        int n = b * 256 + threadIdx.x;
        float2 o = ((const float2*)rpn_obj)[n];
        float m  = fmaxf(o.x, o.y);
        float e0 = expf(o.x - m), e1 = expf(o.y - m);
        float s  = e1 / (e0 + e1);
        if (s > TAUF) {
            unsigned bits = __float_as_uint(s);
            unsigned bk = (bits - 0x3F000000u) >> 13;     // 0..1024
            unsigned slot = atomicAdd(&hist[bk], 1u);
            if (slot < BINCAP)
                bins[bk * BINCAP + slot] =
                    ((unsigned long long)bits << 32) |
                    (unsigned long long)(~(unsigned)n);
        }
        return;
    }
    // weight transposes: fp32 [K][N] -> bf16 [N][K]
    b -= 256;
    const float* W; unsigned short* Wt; int K, N;
    if (b < (FIN / 32) * (HID / 32)) { W = W1; Wt = W1t; K = FIN; N = HID; }
    else { b -= (FIN / 32) * (HID / 32); W = W2; Wt = W2t; K = HID; N = HID; }
    int bn = (b & (N / 32 - 1)) * 32;
    int bk = (b / (N / 32)) * 32;
    int tx = threadIdx.x & 31, ty = threadIdx.x >> 5;     // ty 0..7
#pragma unroll
    for (int r = 0; r < 32; r += 8)
        tile[ty + r][tx] = W[(long)(bk + ty + r) * N + bn + tx];
    __syncthreads();
#pragma unroll
    for (int r = 0; r < 32; r += 8)
        Wt[(long)(bn + ty + r) * K + bk + tx] = f2bf(tile[tx][ty + r]);
}

// ---- single block: threshold + gather + sort + decode + IoU + NMS
__global__ __launch_bounds__(1024)
void select2_kernel(const unsigned* __restrict__ hist,
                    const unsigned long long* __restrict__ bins,
                    const float* __restrict__ rpn_reg,
                    const float* __restrict__ anchors,
                    float* __restrict__ sel,          // 512 x float4
                    float* __restrict__ top_score,    // 512
                    unsigned* __restrict__ valid_g,   // 512
                    unsigned* __restrict__ keep_g) {  // 512
    __shared__ unsigned long long keys[CMAX];        // 16 KB
    __shared__ float4 selS[MAXD];                    // 8 KB
    __shared__ unsigned long long maskS[MAXD * 8];   // 32 KB (scan scratch alias)
    __shared__ unsigned cntS;
    __shared__ unsigned thrS;

    unsigned* Hs  = (unsigned*)maskS;                // 1025 u32
    unsigned* Ssc = (unsigned*)maskS + 1032;         // 1024 u32, no overlap

    int tid = threadIdx.x;
    int wave = tid >> 6, lane = tid & 63;

    // ---- phase A: load hist, suffix-sum buckets 1..1024, find threshold
    if (tid == 0) cntS = 0u;
    for (int i = tid; i < NBUCK; i += 1024) Hs[i] = hist[i];
    __syncthreads();
    unsigned sv = Hs[tid + 1];                       // thread t <-> bucket t+1
    Ssc[tid] = sv;
    __syncthreads();
    for (int d = 1; d < 1024; d <<= 1) {
        unsigned add = (tid + d < 1024) ? Ssc[tid + d] : 0u;
        __syncthreads();
        Ssc[tid] += add;
        __syncthreads();
    }
    if (tid == 0 && Ssc[0] < MAXD) thrS = 0u;
    {
        unsigned Scur = Ssc[tid];
        unsigned Snxt = (tid == 1023) ? 0u : Ssc[tid + 1];
        if (Scur >= MAXD && Snxt < MAXD) thrS = (unsigned)(tid + 1);
    }
    __syncthreads();
    unsigned thr = thrS;

    // ---- phase B: gather candidate keys from bins (order irrelevant)
    for (int b = thr + tid; b < NBUCK; b += 1024) {
        unsigned c = Hs[b]; if (c > BINCAP) c = BINCAP;
        if (c > 0) {
            unsigned pos = atomicAdd(&cntS, c);
            for (unsigned i = 0; i < c && pos + i < CMAX; ++i)
                keys[pos + i] = bins[b * BINCAP + i];
        }
    }
    __syncthreads();
    unsigned cnt = cntS; if (cnt > CMAX) cnt = CMAX;
    int SN = (cnt <= 1024) ? 1024 : CMAX;
    for (int i = tid; i < SN; i += 1024)
        if (i >= (int)cnt) keys[i] = 0ULL;
    __syncthreads();

    // ---- phase C: bitonic sort descending over SN
    for (int k = 2; k <= SN; k <<= 1) {
        for (int j = k >> 1; j > 0; j >>= 1) {
            for (int i = tid; i < SN; i += 1024) {
                int ixj = i ^ j;
                if (ixj > i) {
                    unsigned long long a = keys[i], b = keys[ixj];
                    bool up = ((i & k) == 0);
                    if ((a < b) == up) { keys[i] = b; keys[ixj] = a; }
                }
            }
            __syncthreads();
        }
    }

    // ---- phase D: decode top-512 boxes (same fp32 formulas)
    if (tid < MAXD) {
        unsigned long long e = keys[tid];
        unsigned sbits = (unsigned)(e >> 32);
        bool v = (sbits != 0u);
        unsigned idx = v ? (unsigned)(~(unsigned)e) : 0u;
        int cell = idx >> 2, kk = idx & 3;
        float4 rg = *(const float4*)&rpn_reg[cell * 16 + 4 * kk];
        float4 an = *(const float4*)&anchors[idx * 4];
        float acx = an.x + an.z * 0.5f;
        float acy = an.y + an.w * 0.5f;
        float cx = acx + rg.x * an.z;
        float cy = acy + rg.y * an.w;
        float w  = an.z * expf(rg.z);
        float h  = an.w * expf(rg.w);
        float4 box = make_float4(cx - 0.5f * w, cy - 0.5f * h, w, h);
        selS[tid] = box;
        ((float4*)sel)[tid] = box;
        top_score[tid] = v ? __uint_as_float(sbits) : 0.0f;
        valid_g[tid]   = v ? 1u : 0u;
    }
    __syncthreads();

    // ---- phase E: IoU bit-matrix (only words t <= row's group needed)
    for (int it = 0; it < 32; ++it) {
        int i = wave + 16 * it;
        float4 bi = selS[i];
        float x2i = bi.x + bi.z, y2i = bi.y + bi.w;
        float ai = bi.z * bi.w;
        int g = i >> 6;
        for (int t = 0; t <= g; ++t) {
            float4 bj = selS[t * 64 + lane];
            float x2j = bj.x + bj.z, y2j = bj.y + bj.w;
            float aj = bj.z * bj.w;
            float ix = fmaxf(0.0f, fminf(x2i, x2j) - fmaxf(bi.x, bj.x));
            float iy = fmaxf(0.0f, fminf(y2i, y2j) - fmaxf(bi.y, bj.y));
            float inter = ix * iy;
            float iou = inter / (ai + aj - inter + 1e-8f);
            unsigned long long bal = __ballot(iou > NMS_THR);
            if (lane == 0) maskS[i * 8 + t] = bal;
        }
    }
    __syncthreads();

    // ---- phase F: ballot-pipelined sequential NMS on wave 0
    if (wave == 0) {
        unsigned long long keepw[8];
#pragma unroll
        for (int g = 0; g < 8; ++g) {
            unsigned long long w_cur[8];
#pragma unroll
            for (int t = 0; t < 8; ++t)
                w_cur[t] = (t <= g) ? maskS[(g * 64 + lane) * 8 + t] : 0ULL;
            unsigned long long vb =
                __ballot(((unsigned)(keys[g * 64 + lane] >> 32)) != 0u);
            bool pre = false;
#pragma unroll
            for (int t = 0; t < 8; ++t)
                if (t < g) pre = pre || ((w_cur[t] & keepw[t]) != 0ULL);
            unsigned long long alive = vb & ~__ballot(pre);
            unsigned long long intra = w_cur[g];
            unsigned long long kg = 0ULL;
#pragma unroll
            for (int b = 0; b < 64; ++b) {
                unsigned long long sup = __ballot((intra >> b) & 1ULL);
                if ((alive >> b) & 1ULL) {      // wave-uniform branch
                    kg |= 1ULL << b;
                    alive &= ~sup;
                }
            }
            keepw[g] = kg;
            keep_g[g * 64 + lane] = (unsigned)((kg >> lane) & 1ULL);
        }
    }
}

// ------------------------------------------- ROI align (bf16 output)
__global__ __launch_bounds__(256)
void roialign_kernel(const float* __restrict__ feat,
                     const float* __restrict__ sel,
                     unsigned short* __restrict__ pooled) {
    int mrow = blockIdx.x;
    int c = threadIdx.x;           // channels c and c+256
    float4 b = ((const float4*)sel)[mrow];
    float bx = b.x, by = b.y, bw = b.z, bh = b.w;
    float vmax0[9], vmax1[9];
#pragma unroll
    for (int t = 0; t < 9; ++t) { vmax0[t] = -INFINITY; vmax1[t] = -INFINITY; }
#pragma unroll
    for (int p = 0; p < 6; ++p) {
        float fy = (by + ((float)p + 0.5f) / 6.0f * bh) / 16.0f - 0.5f;
        fy = fminf(fmaxf(fy, 0.0f), 127.0f);
        int y0 = (int)floorf(fy);
        int y1 = min(y0 + 1, 127);
        float wy = fy - (float)y0;
#pragma unroll
        for (int q = 0; q < 6; ++q) {
            float fx = (bx + ((float)q + 0.5f) / 6.0f * bw) / 16.0f - 0.5f;
            fx = fminf(fmaxf(fx, 0.0f), 127.0f);
            int x0 = (int)floorf(fx);
            int x1 = min(x0 + 1, 127);
            float wx = fx - (float)x0;
            const float* f00 = feat + (y0 * WFD + x0) * DFD;
            const float* f01 = feat + (y0 * WFD + x1) * DFD;
            const float* f10 = feat + (y1 * WFD + x0) * DFD;
            const float* f11 = feat + (y1 * WFD + x1) * DFD;
            float w00 = (1.0f - wy) * (1.0f - wx);
            float w01 = (1.0f - wy) * wx;
            float w10 = wy * (1.0f - wx);
            float w11 = wy * wx;
            int t = (p >> 1) * 3 + (q >> 1);
            float v0 = f00[c] * w00 + f01[c] * w01 + f10[c] * w10 + f11[c] * w11;
            float v1 = f00[c + 256] * w00 + f01[c + 256] * w01 +
                       f10[c + 256] * w10 + f11[c + 256] * w11;
            vmax0[t] = fmaxf(vmax0[t], v0);
            vmax1[t] = fmaxf(vmax1[t], v1);
        }
    }
#pragma unroll
    for (int t = 0; t < 9; ++t) {
        pooled[mrow * FIN + t * DFD + c] = f2bf(vmax0[t]);
        pooled[mrow * FIN + t * DFD + c + 256] = f2bf(vmax1[t]);
    }
}

// --------------------------------------- bf16 MFMA GEMM with split-K
#define LDSTRIDE 40
__global__ __launch_bounds__(256)
void mfma_gemm_kernel(const unsigned short* __restrict__ A,
                      const unsigned short* __restrict__ Bt,
                      float* __restrict__ Cpart,
                      int M, int N, int K) {
    __shared__ unsigned short As[64 * LDSTRIDE];
    __shared__ unsigned short Bs[64 * LDSTRIDE];
    int tid = threadIdx.x;
    int wave = tid >> 6, lane = tid & 63;
    int bm = blockIdx.y * 64, bn = blockIdx.x * 64;
    int KC = K / SPLITK;
    int ks = blockIdx.z * KC;

    floatx4 acc[4] = {};
    int lr = tid >> 2;            // 0..63  staging row
    int lk = (tid & 3) << 3;      // 0,8,16,24  staging k-offset
    int frow = lane & 15, quad = lane >> 4;

    const unsigned short* Ap = A + (long)(bm + lr) * K + lk;
    const unsigned short* Bp = Bt + (long)(bn + lr) * K + lk;

    for (int k0 = ks; k0 < ks + KC; k0 += 32) {
        uint4 av = *(const uint4*)(Ap + k0);
        uint4 bv = *(const uint4*)(Bp + k0);
        *(uint4*)&As[lr * LDSTRIDE + lk] = av;
        *(uint4*)&Bs[lr * LDSTRIDE + lk] = bv;
        __syncthreads();
        bf16x8 af = *(const bf16x8*)&As[(wave * 16 + frow) * LDSTRIDE + quad * 8];
#pragma unroll
        for (int t = 0; t < 4; ++t) {
            bf16x8 bfv = *(const bf16x8*)&Bs[(t * 16 + frow) * LDSTRIDE + quad * 8];
            acc[t] = __builtin_amdgcn_mfma_f32_16x16x32_bf16(af, bfv, acc[t], 0, 0, 0);
        }
        __syncthreads();
    }

    float* Cp = Cpart + (long)blockIdx.z * M * N;
#pragma unroll
    for (int t = 0; t < 4; ++t) {
#pragma unroll
        for (int r = 0; r < 4; ++r) {
            int m = bm + wave * 16 + quad * 4 + r;
            int n = bn + t * 16 + frow;
            Cp[(long)m * N + n] = acc[t][r];
        }
    }
}

// --------------------- split-K reduce + bias + relu -> bf16
__global__ __launch_bounds__(256)
void reduce_bias_relu_kernel(const float* __restrict__ Cpart,
                             const float* __restrict__ bias,
                             unsigned short* __restrict__ out_bf,
                             int MN, int N) {
    int i4 = (blockIdx.x * blockDim.x + threadIdx.x) * 4;
    if (i4 >= MN) return;
    float4 s = *(const float4*)&Cpart[i4];
#pragma unroll
    for (int z = 1; z < SPLITK; ++z) {
        float4 p = *(const float4*)&Cpart[(long)z * MN + i4];
        s.x += p.x; s.y += p.y; s.z += p.z; s.w += p.w;
    }
    int n = i4 & (N - 1);
    float4 bi = *(const float4*)&bias[n];
    s.x = fmaxf(s.x + bi.x, 0.0f);
    s.y = fmaxf(s.y + bi.y, 0.0f);
    s.z = fmaxf(s.z + bi.z, 0.0f);
    s.w = fmaxf(s.w + bi.w, 0.0f);
    uint2 o;
    o.x = (unsigned)f2bf(s.x) | ((unsigned)f2bf(s.y) << 16);
    o.y = (unsigned)f2bf(s.z) | ((unsigned)f2bf(s.w) << 16);
    *(uint2*)&out_bf[i4] = o;
}

// --- fused: split-K reduce (GEMM2) + bias2 + relu + W3 dot + epilogue
__global__ __launch_bounds__(256)
void rowhead_kernel(const float* __restrict__ Cpart,
                    const float* __restrict__ b2,
                    const float* __restrict__ W3,
                    const float* __restrict__ b3,
                    const float* __restrict__ sel,
                    const float* __restrict__ top_score,
                    const unsigned* __restrict__ valid,
                    const unsigned* __restrict__ keep,
                    float* __restrict__ out) {
    __shared__ float red[4][4];
    int r = blockIdx.x, t = threadIdx.x;
    int wave = t >> 6, lane = t & 63;
    int c = t * 4;
    const int MN = MAXD * HID;
    float4 s = *(const float4*)&Cpart[(long)r * HID + c];
#pragma unroll
    for (int z = 1; z < SPLITK; ++z) {
        float4 p = *(const float4*)&Cpart[(long)z * MN + (long)r * HID + c];
        s.x += p.x; s.y += p.y; s.z += p.z; s.w += p.w;
    }
    float4 bi = *(const float4*)&b2[c];
    float h[4];
    h[0] = fmaxf(s.x + bi.x, 0.0f);
    h[1] = fmaxf(s.y + bi.y, 0.0f);
    h[2] = fmaxf(s.z + bi.z, 0.0f);
    h[3] = fmaxf(s.w + bi.w, 0.0f);
    float a0 = 0.f, a1 = 0.f, a2 = 0.f, a3 = 0.f;
#pragma unroll
    for (int i = 0; i < 4; ++i) {
        float4 w = *(const float4*)&W3[(c + i) * 4];
        a0 += h[i] * w.x; a1 += h[i] * w.y;
        a2 += h[i] * w.z; a3 += h[i] * w.w;
    }
#pragma unroll
    for (int off = 32; off > 0; off >>= 1) {
        a0 += __shfl_down(a0, off);
        a1 += __shfl_down(a1, off);
        a2 += __shfl_down(a2, off);
        a3 += __shfl_down(a3, off);
    }
    if (lane == 0) {
        red[wave][0] = a0; red[wave][1] = a1;
        red[wave][2] = a2; red[wave][3] = a3;
    }
    __syncthreads();
    if (t == 0) {
        float d0 = red[0][0] + red[1][0] + red[2][0] + red[3][0] + b3[0];
        float d1 = red[0][1] + red[1][1] + red[2][1] + red[3][1] + b3[1];
        float d2 = red[0][2] + red[1][2] + red[2][2] + red[3][2] + b3[2];
        float d3 = red[0][3] + red[1][3] + red[2][3] + red[3][3] + b3[3];
        if (keep[r] != 0u) {
            float4 b = ((const float4*)sel)[r];
            float acx = b.x + 0.5f * b.z;
            float acy = b.y + 0.5f * b.w;
            float cx = acx + d0 * b.z;
            float cy = acy + d1 * b.w;
            float nw = b.z * expf(d2);
            float nh = b.w * expf(d3);
            out[r * 5 + 0] = cx - 0.5f * nw;
            out[r * 5 + 1] = cy - 0.5f * nh;
            out[r * 5 + 2] = nw;
            out[r * 5 + 3] = nh;
            out[r * 5 + 4] = (valid[r] != 0u) ? top_score[r] : 0.0f;
        } else {
            out[r * 5 + 0] = 0.0f;
            out[r * 5 + 1] = 0.0f;
            out[r * 5 + 2] = 0.0f;
            out[r * 5 + 3] = 0.0f;
            out[r * 5 + 4] = 0.0f;
        }
    }
}

// ---------------------------------------------------------------- host
extern "C" void kernel_launch(void* const* d_in, const int* in_sizes, int n_in,
                              void* d_out, int out_size, void* d_ws, size_t ws_size,
                              hipStream_t stream) {
    const float* features = (const float*)d_in[0];
    const float* rpn_obj  = (const float*)d_in[1];
    const float* rpn_reg  = (const float*)d_in[2];
    const float* anchors  = (const float*)d_in[3];
    const float* W1 = (const float*)d_in[4];
    const float* b1 = (const float*)d_in[5];
    const float* W2 = (const float*)d_in[6];
    const float* b2 = (const float*)d_in[7];
    const float* W3 = (const float*)d_in[8];
    const float* b3 = (const float*)d_in[9];
    float* out = (float*)d_out;

    char* ws = (char*)d_ws;
    size_t off = 0;
    auto alloc = [&](size_t bytes) {
        char* p = ws + off;
        off += (bytes + 255) & ~(size_t)255;
        return p;
    };
    unsigned* hist      = (unsigned*)alloc(NBUCK * sizeof(unsigned));
    unsigned long long* bins =
        (unsigned long long*)alloc((size_t)NBUCK * BINCAP * 8);
    float*    sel       = (float*)alloc(MAXD * 4 * sizeof(float));
    float*    top_score = (float*)alloc(MAXD * sizeof(float));
    unsigned* valid     = (unsigned*)alloc(MAXD * sizeof(unsigned));
    unsigned* keep      = (unsigned*)alloc(MAXD * sizeof(unsigned));
    unsigned short* pooled = (unsigned short*)alloc((size_t)MAXD * FIN * 2);
    unsigned short* W1t = (unsigned short*)alloc((size_t)FIN * HID * 2);
    unsigned short* W2t = (unsigned short*)alloc((size_t)HID * HID * 2);
    unsigned short* h1  = (unsigned short*)alloc((size_t)MAXD * HID * 2);
    float*    Cpart     = (float*)alloc((size_t)SPLITK * MAXD * HID * sizeof(float));
    (void)ws_size; (void)in_sizes; (void)n_in; (void)out_size;

    const int TBLOCKS = (FIN / 32) * (HID / 32) + (HID / 32) * (HID / 32);
    init_kernel<<<1, 1024, 0, stream>>>(hist);
    front_kernel<<<256 + TBLOCKS, 256, 0, stream>>>(rpn_obj, hist, bins,
                                                    W1, W1t, W2, W2t);
    select2_kernel<<<1, 1024, 0, stream>>>(hist, bins, rpn_reg, anchors,
                                           sel, top_score, valid, keep);
    roialign_kernel<<<MAXD, 256, 0, stream>>>(features, sel, pooled);

    const int MN = MAXD * HID;
    mfma_gemm_kernel<<<dim3(HID / 64, MAXD / 64, SPLITK), 256, 0, stream>>>(
        pooled, W1t, Cpart, MAXD, HID, FIN);
    reduce_bias_relu_kernel<<<MN / 4 / 256, 256, 0, stream>>>(
        Cpart, b1, h1, MN, HID);
    mfma_gemm_kernel<<<dim3(HID / 64, MAXD / 64, SPLITK), 256, 0, stream>>>(
        h1, W2t, Cpart, MAXD, HID, HID);
    rowhead_kernel<<<MAXD, 256, 0, stream>>>(Cpart, b2, W3, b3, sel,
                                             top_score, valid, keep, out);
}

// Round 6
// 199.842 us; speedup vs baseline: 1.2713x; 1.2219x over previous
//
#include <hip/hip_runtime.h>
#include <math.h>

#define HFD 128
#define WFD 128
#define DFD 512
#define KA  4
#define NA  (HFD*WFD*KA)      // 65536
#define MAXD 512
#define HID 1024
#define FIN 4608              // 3*3*512
#define CMAX 2048
#define NBUCK 1025
#define BINCAP 64
#define TAUF 0.5f
#define NMS_THR 0.3f
#define SPLITK 8

typedef __bf16 bf16x8 __attribute__((ext_vector_type(8)));
typedef float  floatx4 __attribute__((ext_vector_type(4)));

__device__ __forceinline__ unsigned short f2bf(float x) {
    unsigned u = __float_as_uint(x);
    unsigned r = (u + 0x7FFFu + ((u >> 16) & 1u)) >> 16;   // RNE
    return (unsigned short)r;
}

// ------------------------------------------------- zero the histogram
__global__ void init_kernel(unsigned* __restrict__ hist) {
    int t = threadIdx.x;
    for (int i = t; i < NBUCK; i += 1024) hist[i] = 0u;
}

// ---- grid-wide front: score+bucket-bin (blocks 0..255) + transposes
__global__ __launch_bounds__(256)
void front_kernel(const float* __restrict__ rpn_obj,
                  unsigned* __restrict__ hist,
                  unsigned long long* __restrict__ bins,
                  const float* __restrict__ W1,
                  unsigned short* __restrict__ W1t,
                  const float* __restrict__ W2,
                  unsigned short* __restrict__ W2t) {
    __shared__ float tile[32][33];
    int b = blockIdx.x;
    if (b < 256) {
        int n = b * 256 + threadIdx.x;
        float2 o = ((const float2*)rpn_obj)[n];
        float m  = fmaxf(o.x, o.y);
        float e0 = expf(o.x - m), e1 = expf(o.y - m);
        float s  = e1 / (e0 + e1);
        if (s > TAUF) {
            unsigned bits = __float_as_uint(s);
            unsigned bk = (bits - 0x3F000000u) >> 13;     // 0..1024
            unsigned slot = atomicAdd(&hist[bk], 1u);
            if (slot < BINCAP)
                bins[bk * BINCAP + slot] =
                    ((unsigned long long)bits << 32) |
                    (unsigned long long)(~(unsigned)n);
        }
        return;
    }
    b -= 256;
    const float* W; unsigned short* Wt; int K, N;
    if (b < (FIN / 32) * (HID / 32)) { W = W1; Wt = W1t; K = FIN; N = HID; }
    else { b -= (FIN / 32) * (HID / 32); W = W2; Wt = W2t; K = HID; N = HID; }
    int bn = (b & (N / 32 - 1)) * 32;
    int bk = (b / (N / 32)) * 32;
    int tx = threadIdx.x & 31, ty = threadIdx.x >> 5;     // ty 0..7
#pragma unroll
    for (int r = 0; r < 32; r += 8)
        tile[ty + r][tx] = W[(long)(bk + ty + r) * N + bn + tx];
    __syncthreads();
#pragma unroll
    for (int r = 0; r < 32; r += 8)
        Wt[(long)(bn + ty + r) * K + bk + tx] = f2bf(tile[tx][ty + r]);
}

// ---- single block: threshold + parallel gather + sort + decode
__global__ __launch_bounds__(1024)
void tgs_kernel(const unsigned* __restrict__ hist,
                const unsigned long long* __restrict__ bins,
                const float* __restrict__ rpn_reg,
                const float* __restrict__ anchors,
                float* __restrict__ sel,          // 512 x float4
                float* __restrict__ top_score,    // 512
                unsigned* __restrict__ valid_g) { // 512
    __shared__ unsigned long long keys[CMAX];     // 16 KB
    __shared__ unsigned Hs[NBUCK];                // 4.1 KB
    __shared__ unsigned Ssc[1024];                // 4 KB
    __shared__ unsigned cntS;
    __shared__ unsigned thrS;

    int tid = threadIdx.x;
    int wave = tid >> 6, lane = tid & 63;

    // ---- phase A: load hist, suffix-sum buckets 1..1024, find threshold
    if (tid == 0) cntS = 0u;
    for (int i = tid; i < NBUCK; i += 1024) Hs[i] = hist[i];
    __syncthreads();
    unsigned sv = Hs[tid + 1];                    // thread t <-> bucket t+1
    Ssc[tid] = sv;
    __syncthreads();
    for (int d = 1; d < 1024; d <<= 1) {
        unsigned add = (tid + d < 1024) ? Ssc[tid + d] : 0u;
        __syncthreads();
        Ssc[tid] += add;
        __syncthreads();
    }
    if (tid == 0 && Ssc[0] < MAXD) thrS = 0u;
    {
        unsigned Scur = Ssc[tid];
        unsigned Snxt = (tid == 1023) ? 0u : Ssc[tid + 1];
        if (Scur >= MAXD && Snxt < MAXD) thrS = (unsigned)(tid + 1);
    }
    __syncthreads();
    unsigned thr = thrS;

    // ---- phase B: wave-per-bucket PARALLEL gather (lane i -> slot i)
    for (int b = (int)thr + wave; b < NBUCK; b += 16) {
        unsigned c = Hs[b]; if (c > BINCAP) c = BINCAP;
        unsigned base = 0;
        if (lane == 0 && c > 0) base = atomicAdd(&cntS, c);
        base = __shfl(base, 0);
        if (c > 0 && lane < c && base + lane < CMAX)
            keys[base + lane] = bins[(long)b * BINCAP + lane];
    }
    __syncthreads();
    unsigned cnt = cntS; if (cnt > CMAX) cnt = CMAX;
    int SN = (cnt <= 1024) ? 1024 : CMAX;
    for (int i = tid; i < SN; i += 1024)
        if (i >= (int)cnt) keys[i] = 0ULL;
    __syncthreads();

    // ---- phase C: bitonic sort descending over SN
    for (int k = 2; k <= SN; k <<= 1) {
        for (int j = k >> 1; j > 0; j >>= 1) {
            for (int i = tid; i < SN; i += 1024) {
                int ixj = i ^ j;
                if (ixj > i) {
                    unsigned long long a = keys[i], b = keys[ixj];
                    bool up = ((i & k) == 0);
                    if ((a < b) == up) { keys[i] = b; keys[ixj] = a; }
                }
            }
            __syncthreads();
        }
    }

    // ---- phase D: decode top-512 boxes (same fp32 formulas)
    if (tid < MAXD) {
        unsigned long long e = keys[tid];
        unsigned sbits = (unsigned)(e >> 32);
        bool v = (sbits != 0u);
        unsigned idx = v ? (unsigned)(~(unsigned)e) : 0u;
        int cell = idx >> 2, kk = idx & 3;
        float4 rg = *(const float4*)&rpn_reg[cell * 16 + 4 * kk];
        float4 an = *(const float4*)&anchors[idx * 4];
        float acx = an.x + an.z * 0.5f;
        float acy = an.y + an.w * 0.5f;
        float cx = acx + rg.x * an.z;
        float cy = acy + rg.y * an.w;
        float w  = an.z * expf(rg.z);
        float h  = an.w * expf(rg.w);
        ((float4*)sel)[tid] = make_float4(cx - 0.5f * w, cy - 0.5f * h, w, h);
        top_score[tid] = v ? __uint_as_float(sbits) : 0.0f;
        valid_g[tid]   = v ? 1u : 0u;
    }
}

// ---------------------------------------------------- IoU bitmask
__global__ __launch_bounds__(512)
void iou_mask_kernel(const float* __restrict__ sel,
                     unsigned long long* __restrict__ mask) {
    int i = blockIdx.x;
    int j = threadIdx.x;
    float4 bi = ((const float4*)sel)[i];
    float4 bj = ((const float4*)sel)[j];
    float x2i = bi.x + bi.z, y2i = bi.y + bi.w;
    float x2j = bj.x + bj.z, y2j = bj.y + bj.w;
    float ai = bi.z * bi.w, aj = bj.z * bj.w;
    float ix = fmaxf(0.0f, fminf(x2i, x2j) - fmaxf(bi.x, bj.x));
    float iy = fmaxf(0.0f, fminf(y2i, y2j) - fmaxf(bi.y, bj.y));
    float inter = ix * iy;
    float iou = inter / (ai + aj - inter + 1e-8f);
    unsigned long long bal = __ballot(iou > NMS_THR);
    if ((j & 63) == 0) mask[i * 8 + (j >> 6)] = bal;
}

// ------------------- sequential NMS, ballot-pipelined (1 wave)
__global__ __launch_bounds__(64)
void nms_scan_kernel(const unsigned long long* __restrict__ mask,
                     const unsigned* __restrict__ valid,
                     unsigned* __restrict__ keep) {
    int lane = threadIdx.x;
    unsigned long long w[8][8];   // [g][t<=g] : mask word t of row 64g+lane
#pragma unroll
    for (int g = 0; g < 8; ++g)
#pragma unroll
        for (int t = 0; t < 8; ++t)
            if (t <= g) w[g][t] = mask[(g * 64 + lane) * 8 + t];
    unsigned long long vb[8];
#pragma unroll
    for (int g = 0; g < 8; ++g)
        vb[g] = __ballot(valid[g * 64 + lane] != 0u);

    unsigned long long keepw[8];
#pragma unroll
    for (int g = 0; g < 8; ++g) {
        bool pre = false;
#pragma unroll
        for (int t = 0; t < 8; ++t)
            if (t < g) pre = pre || ((w[g][t] & keepw[t]) != 0ULL);
        unsigned long long alive = vb[g] & ~__ballot(pre);
        unsigned long long intra = w[g][g];
        unsigned long long kg = 0ULL;
#pragma unroll
        for (int b = 0; b < 64; ++b) {
            unsigned long long sup = __ballot((intra >> b) & 1ULL);
            if ((alive >> b) & 1ULL) {      // wave-uniform branch
                kg |= 1ULL << b;
                alive &= ~sup;
            }
        }
        keepw[g] = kg;
        keep[g * 64 + lane] = (unsigned)((kg >> lane) & 1ULL);
    }
}

// ------------------------------------------- ROI align (bf16 output)
__global__ __launch_bounds__(256)
void roialign_kernel(const float* __restrict__ feat,
                     const float* __restrict__ sel,
                     unsigned short* __restrict__ pooled) {
    int mrow = blockIdx.x;
    int c = threadIdx.x;           // channels c and c+256
    float4 b = ((const float4*)sel)[mrow];
    float bx = b.x, by = b.y, bw = b.z, bh = b.w;
    float vmax0[9], vmax1[9];
#pragma unroll
    for (int t = 0; t < 9; ++t) { vmax0[t] = -INFINITY; vmax1[t] = -INFINITY; }
#pragma unroll
    for (int p = 0; p < 6; ++p) {
        float fy = (by + ((float)p + 0.5f) / 6.0f * bh) / 16.0f - 0.5f;
        fy = fminf(fmaxf(fy, 0.0f), 127.0f);
        int y0 = (int)floorf(fy);
        int y1 = min(y0 + 1, 127);
        float wy = fy - (float)y0;
#pragma unroll
        for (int q = 0; q < 6; ++q) {
            float fx = (bx + ((float)q + 0.5f) / 6.0f * bw) / 16.0f - 0.5f;
            fx = fminf(fmaxf(fx, 0.0f), 127.0f);
            int x0 = (int)floorf(fx);
            int x1 = min(x0 + 1, 127);
            float wx = fx - (float)x0;
            const float* f00 = feat + (y0 * WFD + x0) * DFD;
            const float* f01 = feat + (y0 * WFD + x1) * DFD;
            const float* f10 = feat + (y1 * WFD + x0) * DFD;
            const float* f11 = feat + (y1 * WFD + x1) * DFD;
            float w00 = (1.0f - wy) * (1.0f - wx);
            float w01 = (1.0f - wy) * wx;
            float w10 = wy * (1.0f - wx);
            float w11 = wy * wx;
            int t = (p >> 1) * 3 + (q >> 1);
            float v0 = f00[c] * w00 + f01[c] * w01 + f10[c] * w10 + f11[c] * w11;
            float v1 = f00[c + 256] * w00 + f01[c + 256] * w01 +
                       f10[c + 256] * w10 + f11[c + 256] * w11;
            vmax0[t] = fmaxf(vmax0[t], v0);
            vmax1[t] = fmaxf(vmax1[t], v1);
        }
    }
#pragma unroll
    for (int t = 0; t < 9; ++t) {
        pooled[mrow * FIN + t * DFD + c] = f2bf(vmax0[t]);
        pooled[mrow * FIN + t * DFD + c + 256] = f2bf(vmax1[t]);
    }
}

// --------------------------------------- bf16 MFMA GEMM with split-K
#define LDSTRIDE 40
__global__ __launch_bounds__(256)
void mfma_gemm_kernel(const unsigned short* __restrict__ A,
                      const unsigned short* __restrict__ Bt,
                      float* __restrict__ Cpart,
                      int M, int N, int K) {
    __shared__ unsigned short As[64 * LDSTRIDE];
    __shared__ unsigned short Bs[64 * LDSTRIDE];
    int tid = threadIdx.x;
    int wave = tid >> 6, lane = tid & 63;
    int bm = blockIdx.y * 64, bn = blockIdx.x * 64;
    int KC = K / SPLITK;
    int ks = blockIdx.z * KC;

    floatx4 acc[4] = {};
    int lr = tid >> 2;            // 0..63  staging row
    int lk = (tid & 3) << 3;      // 0,8,16,24  staging k-offset
    int frow = lane & 15, quad = lane >> 4;

    const unsigned short* Ap = A + (long)(bm + lr) * K + lk;
    const unsigned short* Bp = Bt + (long)(bn + lr) * K + lk;

    for (int k0 = ks; k0 < ks + KC; k0 += 32) {
        uint4 av = *(const uint4*)(Ap + k0);
        uint4 bv = *(const uint4*)(Bp + k0);
        *(uint4*)&As[lr * LDSTRIDE + lk] = av;
        *(uint4*)&Bs[lr * LDSTRIDE + lk] = bv;
        __syncthreads();
        bf16x8 af = *(const bf16x8*)&As[(wave * 16 + frow) * LDSTRIDE + quad * 8];
#pragma unroll
        for (int t = 0; t < 4; ++t) {
            bf16x8 bfv = *(const bf16x8*)&Bs[(t * 16 + frow) * LDSTRIDE + quad * 8];
            acc[t] = __builtin_amdgcn_mfma_f32_16x16x32_bf16(af, bfv, acc[t], 0, 0, 0);
        }
        __syncthreads();
    }

    float* Cp = Cpart + (long)blockIdx.z * M * N;
#pragma unroll
    for (int t = 0; t < 4; ++t) {
#pragma unroll
        for (int r = 0; r < 4; ++r) {
            int m = bm + wave * 16 + quad * 4 + r;
            int n = bn + t * 16 + frow;
            Cp[(long)m * N + n] = acc[t][r];
        }
    }
}

// --------------------- split-K reduce + bias + relu -> bf16
__global__ __launch_bounds__(256)
void reduce_bias_relu_kernel(const float* __restrict__ Cpart,
                             const float* __restrict__ bias,
                             unsigned short* __restrict__ out_bf,
                             int MN, int N) {
    int i4 = (blockIdx.x * blockDim.x + threadIdx.x) * 4;
    if (i4 >= MN) return;
    float4 s = *(const float4*)&Cpart[i4];
#pragma unroll
    for (int z = 1; z < SPLITK; ++z) {
        float4 p = *(const float4*)&Cpart[(long)z * MN + i4];
        s.x += p.x; s.y += p.y; s.z += p.z; s.w += p.w;
    }
    int n = i4 & (N - 1);
    float4 bi = *(const float4*)&bias[n];
    s.x = fmaxf(s.x + bi.x, 0.0f);
    s.y = fmaxf(s.y + bi.y, 0.0f);
    s.z = fmaxf(s.z + bi.z, 0.0f);
    s.w = fmaxf(s.w + bi.w, 0.0f);
    uint2 o;
    o.x = (unsigned)f2bf(s.x) | ((unsigned)f2bf(s.y) << 16);
    o.y = (unsigned)f2bf(s.z) | ((unsigned)f2bf(s.w) << 16);
    *(uint2*)&out_bf[i4] = o;
}

// --- fused: split-K reduce (GEMM2) + bias2 + relu + W3 dot + epilogue
__global__ __launch_bounds__(256)
void rowhead_kernel(const float* __restrict__ Cpart,
                    const float* __restrict__ b2,
                    const float* __restrict__ W3,
                    const float* __restrict__ b3,
                    const float* __restrict__ sel,
                    const float* __restrict__ top_score,
                    const unsigned* __restrict__ valid,
                    const unsigned* __restrict__ keep,
                    float* __restrict__ out) {
    __shared__ float red[4][4];
    int r = blockIdx.x, t = threadIdx.x;
    int wave = t >> 6, lane = t & 63;
    int c = t * 4;
    const int MN = MAXD * HID;
    float4 s = *(const float4*)&Cpart[(long)r * HID + c];
#pragma unroll
    for (int z = 1; z < SPLITK; ++z) {
        float4 p = *(const float4*)&Cpart[(long)z * MN + (long)r * HID + c];
        s.x += p.x; s.y += p.y; s.z += p.z; s.w += p.w;
    }
    float4 bi = *(const float4*)&b2[c];
    float h[4];
    h[0] = fmaxf(s.x + bi.x, 0.0f);
    h[1] = fmaxf(s.y + bi.y, 0.0f);
    h[2] = fmaxf(s.z + bi.z, 0.0f);
    h[3] = fmaxf(s.w + bi.w, 0.0f);
    float a0 = 0.f, a1 = 0.f, a2 = 0.f, a3 = 0.f;
#pragma unroll
    for (int i = 0; i < 4; ++i) {
        float4 w = *(const float4*)&W3[(c + i) * 4];
        a0 += h[i] * w.x; a1 += h[i] * w.y;
        a2 += h[i] * w.z; a3 += h[i] * w.w;
    }
#pragma unroll
    for (int off = 32; off > 0; off >>= 1) {
        a0 += __shfl_down(a0, off);
        a1 += __shfl_down(a1, off);
        a2 += __shfl_down(a2, off);
        a3 += __shfl_down(a3, off);
    }
    if (lane == 0) {
        red[wave][0] = a0; red[wave][1] = a1;
        red[wave][2] = a2; red[wave][3] = a3;
    }
    __syncthreads();
    if (t == 0) {
        float d0 = red[0][0] + red[1][0] + red[2][0] + red[3][0] + b3[0];
        float d1 = red[0][1] + red[1][1] + red[2][1] + red[3][1] + b3[1];
        float d2 = red[0][2] + red[1][2] + red[2][2] + red[3][2] + b3[2];
        float d3 = red[0][3] + red[1][3] + red[2][3] + red[3][3] + b3[3];
        if (keep[r] != 0u) {
            float4 b = ((const float4*)sel)[r];
            float acx = b.x + 0.5f * b.z;
            float acy = b.y + 0.5f * b.w;
            float cx = acx + d0 * b.z;
            float cy = acy + d1 * b.w;
            float nw = b.z * expf(d2);
            float nh = b.w * expf(d3);
            out[r * 5 + 0] = cx - 0.5f * nw;
            out[r * 5 + 1] = cy - 0.5f * nh;
            out[r * 5 + 2] = nw;
            out[r * 5 + 3] = nh;
            out[r * 5 + 4] = (valid[r] != 0u) ? top_score[r] : 0.0f;
        } else {
            out[r * 5 + 0] = 0.0f;
            out[r * 5 + 1] = 0.0f;
            out[r * 5 + 2] = 0.0f;
            out[r * 5 + 3] = 0.0f;
            out[r * 5 + 4] = 0.0f;
        }
    }
}

// ---------------------------------------------------------------- host
extern "C" void kernel_launch(void* const* d_in, const int* in_sizes, int n_in,
                              void* d_out, int out_size, void* d_ws, size_t ws_size,
                              hipStream_t stream) {
    const float* features = (const float*)d_in[0];
    const float* rpn_obj  = (const float*)d_in[1];
    const float* rpn_reg  = (const float*)d_in[2];
    const float* anchors  = (const float*)d_in[3];
    const float* W1 = (const float*)d_in[4];
    const float* b1 = (const float*)d_in[5];
    const float* W2 = (const float*)d_in[6];
    const float* b2 = (const float*)d_in[7];
    const float* W3 = (const float*)d_in[8];
    const float* b3 = (const float*)d_in[9];
    float* out = (float*)d_out;

    char* ws = (char*)d_ws;
    size_t off = 0;
    auto alloc = [&](size_t bytes) {
        char* p = ws + off;
        off += (bytes + 255) & ~(size_t)255;
        return p;
    };
    unsigned* hist      = (unsigned*)alloc(NBUCK * sizeof(unsigned));
    unsigned long long* bins =
        (unsigned long long*)alloc((size_t)NBUCK * BINCAP * 8);
    float*    sel       = (float*)alloc(MAXD * 4 * sizeof(float));
    float*    top_score = (float*)alloc(MAXD * sizeof(float));
    unsigned* valid     = (unsigned*)alloc(MAXD * sizeof(unsigned));
    unsigned* keep      = (unsigned*)alloc(MAXD * sizeof(unsigned));
    unsigned long long* mask = (unsigned long long*)alloc(MAXD * 8 * 8);
    unsigned short* pooled = (unsigned short*)alloc((size_t)MAXD * FIN * 2);
    unsigned short* W1t = (unsigned short*)alloc((size_t)FIN * HID * 2);
    unsigned short* W2t = (unsigned short*)alloc((size_t)HID * HID * 2);
    unsigned short* h1  = (unsigned short*)alloc((size_t)MAXD * HID * 2);
    float*    Cpart     = (float*)alloc((size_t)SPLITK * MAXD * HID * sizeof(float));
    (void)ws_size; (void)in_sizes; (void)n_in; (void)out_size;

    const int TBLOCKS = (FIN / 32) * (HID / 32) + (HID / 32) * (HID / 32);
    init_kernel<<<1, 1024, 0, stream>>>(hist);
    front_kernel<<<256 + TBLOCKS, 256, 0, stream>>>(rpn_obj, hist, bins,
                                                    W1, W1t, W2, W2t);
    tgs_kernel<<<1, 1024, 0, stream>>>(hist, bins, rpn_reg, anchors,
                                       sel, top_score, valid);
    iou_mask_kernel<<<MAXD, 512, 0, stream>>>(sel, mask);
    nms_scan_kernel<<<1, 64, 0, stream>>>(mask, valid, keep);
    roialign_kernel<<<MAXD, 256, 0, stream>>>(features, sel, pooled);

    const int MN = MAXD * HID;
    mfma_gemm_kernel<<<dim3(HID / 64, MAXD / 64, SPLITK), 256, 0, stream>>>(
        pooled, W1t, Cpart, MAXD, HID, FIN);
    reduce_bias_relu_kernel<<<MN / 4 / 256, 256, 0, stream>>>(
        Cpart, b1, h1, MN, HID);
    mfma_gemm_kernel<<<dim3(HID / 64, MAXD / 64, SPLITK), 256, 0, stream>>>(
        h1, W2t, Cpart, MAXD, HID, HID);
    rowhead_kernel<<<MAXD, 256, 0, stream>>>(Cpart, b2, W3, b3, sel,
                                             top_score, valid, keep, out);
}